// Round 14
// baseline (582.838 us; speedup 1.0000x reference)
//
#include <hip/hip_runtime.h>
#include <hip/hip_bf16.h>
#include <stdint.h>

// Problem dims (fixed by reference)
#define Bq    8192
#define Hh    8
#define Dd    16
#define Kk    16
#define Nn    4096
#define DFf   16
#define ROWS  (Bq*Hh)          // 65536
#define COLS  (Dd*Kk)          // 256
#define EPSF  1e-6f

typedef unsigned long long u64;
typedef unsigned int u32;
typedef __attribute__((ext_vector_type(8)))  short bf16x8;
typedef __attribute__((ext_vector_type(16))) float f32x16;

// async global->LDS, 16B per lane; LDS dest = wave-uniform base + lane*16
#define GLOAD_LDS(g, l) __builtin_amdgcn_global_load_lds( \
    (const __attribute__((address_space(1))) u32*)(g), \
    (__attribute__((address_space(3))) u32*)(l), 16, 0, 0)

// ---------- helpers ----------
__device__ __forceinline__ float dot4(float4 a, float4 b) {
    return fmaf(a.x, b.x, fmaf(a.y, b.y, fmaf(a.z, b.z, a.w * b.w)));
}
__device__ __forceinline__ float wave_sum(float v) {
    #pragma unroll
    for (int m = 32; m > 0; m >>= 1) v += __shfl_xor(v, m, 64);
    return v;
}
__device__ __forceinline__ u32 f32_sortable(float f) {
    u32 u = __float_as_uint(f);
    return (u & 0x80000000u) ? ~u : (u | 0x80000000u);
}
// pack 2 floats -> 2 bf16 (RNE); low 16 bits = a
__device__ __forceinline__ u32 pk2(float a, float b) {
    union { __hip_bfloat162 h; u32 u; } v;
    v.h = __float22bfloat162_rn(make_float2(a, b));
    return v.u;
}
// exact fp32 rerank, R2's accepted expression tree (sequential fmaf over 64 float4s)
__device__ __forceinline__ void exact_rerank(const float* __restrict__ X,
                                             const float* __restrict__ CB,
                                             const float* __restrict__ xx,
                                             const float* __restrict__ cbn,
                                             int row, int col,
                                             u64* __restrict__ best) {
    const float4* xp = (const float4*)(X + (size_t)row * COLS);
    const float4* cp = (const float4*)(CB + (size_t)col * COLS);
    float d = 0.f;
    #pragma unroll 8
    for (int q = 0; q < 64; ++q) {
        float4 a = xp[q], b = cp[q];
        d = fmaf(a.x, b.x, d); d = fmaf(a.y, b.y, d);
        d = fmaf(a.z, b.z, d); d = fmaf(a.w, b.w, d);
    }
    float d2e = fmaf(-2.f, d, xx[row]) + cbn[col];
    u64 pk = ((u64)f32_sortable(d2e) << 32) | (u32)col;
    atomicMin(&best[row], pk);
}

// ---------- kernel 0: xx[r], X->bf16 (row-major), init best/cbn_max ----------
__global__ __launch_bounds__(256) void k_prep(const float* __restrict__ X,
                                              short* __restrict__ Xh,
                                              float* __restrict__ xx,
                                              u64* __restrict__ best,
                                              u32* __restrict__ cbn_max) {
    int r    = blockIdx.x * 4 + (threadIdx.x >> 6);
    int lane = threadIdx.x & 63;
    float4 v = *reinterpret_cast<const float4*>(X + (size_t)r * COLS + lane * 4);
    uint2 p; p.x = pk2(v.x, v.y); p.y = pk2(v.z, v.w);
    *reinterpret_cast<uint2*>(Xh + (size_t)r * COLS + lane * 4) = p;
    float s = wave_sum(v.x*v.x + v.y*v.y + v.z*v.z + v.w*v.w);
    if (lane == 0) { xx[r] = s; best[r] = ~0ull; }
    if (blockIdx.x == 0 && threadIdx.x == 0) *cbn_max = 0u;
}

// ---------- kernel 1: codebook fp32 + 32x32-FRAGMENT bf16 + cbn (+acc-order copy) ----------
// CBf layout (R10/R13, HW-verified): per 32-code tile (16 KB), frag f = kstep
// (0..15) is 1 KB: lane l = h*32 + c holds code row (tile*32 + c),
// k = kstep*16 + h*8 .. +8.  cbn_f = cbn permuted into acc order:
// cbn_f[tile*32 + h*16 + r] = cbn[tile*32 + crow(r,h)], crow = (r&3)+8*(r>>2)+4h.
__global__ __launch_bounds__(256) void k_codebook(const float* __restrict__ fc,
                                                  const float* __restrict__ Wi,
                                                  const float* __restrict__ Wo,
                                                  float* __restrict__ CB,
                                                  short* __restrict__ CBf,
                                                  float* __restrict__ cbn,
                                                  float* __restrict__ cbn_f,
                                                  u32* __restrict__ cbn_max) {
    int n = blockIdx.x, tid = threadIdx.x;
    int o = tid >> 4, k = tid & 15;
    __shared__ float fcs[256], wis[256], wos[256], hs[256], sq[256];
    __shared__ short cvs_sh[256];
    fcs[tid] = fc[(size_t)n * 256 + tid];
    wis[tid] = Wi[tid];
    wos[tid] = Wo[tid];
    __syncthreads();
    float hp = 0.f;
    #pragma unroll
    for (int i = 0; i < 16; ++i) hp = fmaf(wis[o*16 + i], fcs[i*16 + k], hp);
    hs[tid] = hp;
    __syncthreads();
    float h0 = hs[o * 16];
    float x3 = h0 * h0 * h0;
    float inner = 0.7978845608028654f * fmaf(0.044715f, x3, h0);
    float g = 0.5f * h0 * (1.f + tanhf(inner));
    float hg = hp * g;
    __syncthreads();
    hs[tid] = hg;
    __syncthreads();
    float cv = 0.f;
    #pragma unroll
    for (int i = 0; i < 16; ++i) cv = fmaf(wos[o*16 + i], hs[i*16 + k], cv);
    CB[(size_t)n * 256 + tid] = cv;
    { union { __hip_bfloat16 h; short s; } c; c.h = __float2bfloat16(cv);
      cvs_sh[tid] = c.s; }
    sq[tid] = cv * cv;
    __syncthreads();
    #pragma unroll
    for (int st = 128; st > 0; st >>= 1) {
        if (tid < st) sq[tid] += sq[tid + st];
        __syncthreads();
    }
    if (tid == 0) {
        cbn[n] = sq[0];
        atomicMax(cbn_max, __float_as_uint(sq[0]));
        int tile = n >> 5, c = n & 31;
        int h = (c >> 2) & 1, r = (c & 3) | ((c >> 3) << 2);
        cbn_f[tile * 32 + h * 16 + r] = sq[0];
    }
    // swizzled write: 32 chunks of 8 bf16 -> 32x32-fragment slots
    if (tid < 32) {
        int kc = tid;                      // 8-short chunk, k = kc*8
        int tile = n >> 5, c = n & 31;
        int kstep = kc >> 1, h = kc & 1;
        size_t off = (size_t)tile * 8192 + kstep * 512 + h * 256 + c * 8;
        *reinterpret_cast<uint4*>(CBf + off) =
            *reinterpret_cast<const uint4*>(&cvs_sh[kc * 8]);
    }
}

// ---------- kernel 2: swapped-operand 32x32 screen, 4 blocks/CU ----------
// 1024 blocks x 256 threads: bm = bid>>1 (128 x-rows), half = bid&1 (2048
// codes, 64 tiles). Same per-wave structure as R13 (HW-verified): lane owns
// one x-row; mfma(code_frag, x_frag); register-only epilogue + 1 shfl.
// LDS shrunk 72 -> 40 KB for 4 blocks/CU (16 waves/CU, 2x R13): DOUBLE
// buffer (2x16 KB) + half-cbn (8 KB); candidates in 6 static reg slots
// (R5-proven). Counted-vmcnt depth-1 pipeline:
//   prologue: STAGE(t0,buf0), STAGE(t1,buf1)           (8 issues/thread)
//   step t:   s_waitcnt vmcnt(4)  -> tile t landed (t+1 in flight)
//             s_barrier; 16 ds_read_b128 + 16 MFMA + epilogue; s_barrier
//             STAGE(t+2 (wrapped), buf t&1)            (count stays uniform)
// Slack per stage = one full step >> L2 latency. Partial-sweep collection
// safety (R11-proven): block-local running rmin includes the current tile,
// so the true argmin and all exact ties enter some block's candidate set;
// exact fp32 rerank (R2 tree) + packed atomicMin(best) merges.
__global__ __launch_bounds__(256, 2) void k_screen_fused(
        const short* __restrict__ Xh,
        const short* __restrict__ CBf,
        const float* __restrict__ X,
        const float* __restrict__ CB,
        const float* __restrict__ cbn,
        const float* __restrict__ cbn_f,
        const float* __restrict__ xx,
        u64* __restrict__ best,
        const u32* __restrict__ cbn_max) {
    __shared__ __align__(16) short Bs[2][8192];   // 2 x 16 KB code tiles
    __shared__ float cbn_fs[2048];                // 8 KB, acc-order, this half

    const int tid  = threadIdx.x;
    const int lane = tid & 63;
    const int w    = tid >> 6;           // wave 0..3
    const int cl   = lane & 31;          // this lane's x-row (D col)
    const int kh   = lane >> 5;          // k-half / code-half
    const int half = blockIdx.x & 1;     // codebook half
    const int tgBase = half * 64;        // first global tile of this half
    const int bmBase = (blockIdx.x >> 1) * 128;
    const int myrow  = bmBase + w * 32 + cl;

#define STAGE(tg_, buf) do { \
        int _t = (tg_); \
        _Pragma("unroll") \
        for (int _i = 0; _i < 4; ++_i) { \
            int _f = _i * 4 + w; \
            const short* _g = CBf + (size_t)_t * 8192 + _f * 512 + lane * 8; \
            GLOAD_LDS(_g, &Bs[(buf)][_f * 512]); \
        } \
    } while (0)

    // half of cbn_f -> LDS (acc-order, 2048 codes), 8 floats per thread
    {
        const float* cfp = cbn_f + half * 2048;
        float4 c0 = *reinterpret_cast<const float4*>(&cfp[tid * 8]);
        float4 c1 = *reinterpret_cast<const float4*>(&cfp[tid * 8 + 4]);
        *reinterpret_cast<float4*>(&cbn_fs[tid * 8])     = c0;
        *reinterpret_cast<float4*>(&cbn_fs[tid * 8 + 4]) = c1;
    }

    // X fragments (B-operand): af[kstep], lane holds x-row myrow,
    // k = kstep*16 + kh*8 .. +8
    bf16x8 af[16];
    {
        const short* ap = Xh + ((size_t)myrow << 8) + kh * 8;
        #pragma unroll
        for (int ks = 0; ks < 16; ++ks)
            af[ks] = *reinterpret_cast<const bf16x8*>(ap + ks * 16);
    }

    // lane-local threshold slack (exact per-row)
    float dlt, rmin = 1e30f;
    {
        float xr = xx[myrow];
        dlt = fmaf(0.003f, sqrtf(xr * __uint_as_float(*cbn_max)), 0.01f);
    }

    __syncthreads();            // cbn_fs visible; vmcnt drained to 0 (prologue)

    STAGE(tgBase + 0, 0); STAGE(tgBase + 1, 1);   // 8 issues/thread outstanding

    u32 c0 = 0, c1 = 0, c2 = 0, c3 = 0, c4 = 0, c5 = 0;
    int ccnt = 0;

    for (int t = 0; t < 64; ++t) {
        asm volatile("s_waitcnt vmcnt(4)" ::: "memory");
        __builtin_amdgcn_sched_barrier(0);
        __builtin_amdgcn_s_barrier();               // (A) buf[t&1] ready
        __builtin_amdgcn_sched_barrier(0);

        f32x16 acc;
        #pragma unroll
        for (int r = 0; r < 16; ++r) acc[r] = 0.f;

        const short* Bt = &Bs[t & 1][0];
        #pragma unroll
        for (int ks = 0; ks < 16; ++ks) {
            bf16x8 cf = *reinterpret_cast<const bf16x8*>(&Bt[ks * 512 + lane * 8]);
            acc = __builtin_amdgcn_mfma_f32_32x32x16_bf16(cf, af[ks], acc, 0, 0, 0);
        }

        // epilogue: g[r] = -2*dot + cbn; codes crow(r,kh) of tile tgBase+t
        float cbnv[16];
        #pragma unroll
        for (int q = 0; q < 4; ++q)
            *reinterpret_cast<float4*>(&cbnv[q * 4]) =
                *reinterpret_cast<const float4*>(&cbn_fs[t * 32 + kh * 16 + q * 4]);
        float gv[16], m = 1e30f;
        #pragma unroll
        for (int r = 0; r < 16; ++r) {
            gv[r] = fmaf(-2.f, acc[r], cbnv[r]);
            m = fminf(m, gv[r]);
        }
        m = fminf(m, __shfl_xor(m, 32, 64));        // other code-half, same row
        rmin = fminf(rmin, m);                      // running min incl. this tile
        float thr = rmin + dlt;
        #pragma unroll
        for (int r = 0; r < 16; ++r) {
            if (gv[r] <= thr) {
                u32 code = (u32)((tgBase + t) * 32 + (r & 3) + 8 * (r >> 2) + 4 * kh);
                if      (ccnt == 0) c0 = code;
                else if (ccnt == 1) c1 = code;
                else if (ccnt == 2) c2 = code;
                else if (ccnt == 3) c3 = code;
                else if (ccnt == 4) c4 = code;
                else if (ccnt == 5) c5 = code;
                else exact_rerank(X, CB, xx, cbn, myrow, (int)code, best); // ~never
                ++ccnt;
            }
        }

        __builtin_amdgcn_sched_barrier(0);
        __builtin_amdgcn_s_barrier();               // (B) buf[t&1] free
        __builtin_amdgcn_sched_barrier(0);
        STAGE(tgBase + ((t + 2) & 63), t & 1);      // wrap keeps count uniform
    }

    // post-loop: exact fp32 rerank of buffered candidates (R2's tree)
    if (ccnt > 0) exact_rerank(X, CB, xx, cbn, myrow, (int)c0, best);
    if (ccnt > 1) exact_rerank(X, CB, xx, cbn, myrow, (int)c1, best);
    if (ccnt > 2) exact_rerank(X, CB, xx, cbn, myrow, (int)c2, best);
    if (ccnt > 3) exact_rerank(X, CB, xx, cbn, myrow, (int)c3, best);
    if (ccnt > 4) exact_rerank(X, CB, xx, cbn, myrow, (int)c4, best);
    if (ccnt > 5) exact_rerank(X, CB, xx, cbn, myrow, (int)c5, best);
#undef STAGE
}

// ---------- kernel 3: gather e, Householder STE ----------
__global__ __launch_bounds__(256) void k_epilogue(const float* __restrict__ X,
                                                  const float* __restrict__ CB,
                                                  const u64* __restrict__ best,
                                                  float* __restrict__ Eout,
                                                  float* __restrict__ Sout) {
    int r    = blockIdx.x * 4 + (threadIdx.x >> 6);
    int lane = threadIdx.x & 63;
    int idx  = (int)(best[r] & 0xffffffffull);

    float4 xv = *reinterpret_cast<const float4*>(X  + (size_t)r   * COLS + lane * 4);
    float4 ev = *reinterpret_cast<const float4*>(CB + (size_t)idx * COLS + lane * 4);

    float xn2 = wave_sum(dot4(xv, xv));
    float en2 = wave_sum(dot4(ev, ev));
    float xn = sqrtf(xn2), en = sqrtf(en2);
    float invx = 1.f / fmaxf(xn, EPSF);
    float inve = 1.f / fmaxf(en, EPSF);

    float4 xd, ed, sd0;
    xd.x = xv.x*invx; xd.y = xv.y*invx; xd.z = xv.z*invx; xd.w = xv.w*invx;
    ed.x = ev.x*inve; ed.y = ev.y*inve; ed.z = ev.z*inve; ed.w = ev.w*inve;
    sd0.x = xd.x+ed.x; sd0.y = xd.y+ed.y; sd0.z = xd.z+ed.z; sd0.w = xd.w+ed.w;

    float sdn2 = wave_sum(dot4(sd0, sd0));
    float p1   = wave_sum(dot4(sd0, xv));
    float p2   = wave_sum(dot4(xd,  xv));
    float invs = 1.f / fmaxf(sqrtf(sdn2), EPSF);

    float csd = -2.f * invs * invs * p1;
    float ced =  2.f * p2;
    float4 rr;
    rr.x = fmaf(csd, sd0.x, fmaf(ced, ed.x, xv.x));
    rr.y = fmaf(csd, sd0.y, fmaf(ced, ed.y, xv.y));
    rr.z = fmaf(csd, sd0.z, fmaf(ced, ed.z, xv.z));
    rr.w = fmaf(csd, sd0.w, fmaf(ced, ed.w, xv.w));
    float sc = en * invx;
    float4 sv; sv.x = rr.x*sc; sv.y = rr.y*sc; sv.z = rr.z*sc; sv.w = rr.w*sc;

    *reinterpret_cast<float4*>(Eout + (size_t)r * COLS + lane * 4) = ev;
    *reinterpret_cast<float4*>(Sout + (size_t)r * COLS + lane * 4) = sv;
}

// ---------- launcher ----------
extern "C" void kernel_launch(void* const* d_in, const int* in_sizes, int n_in,
                              void* d_out, int out_size, void* d_ws, size_t ws_size,
                              hipStream_t stream) {
    const float* x  = (const float*)d_in[0];
    const float* fc = (const float*)d_in[1];
    const float* Wi = (const float*)d_in[2];
    const float* Wo = (const float*)d_in[3];

    // ws layout (~5 MB)
    char* ws = (char*)d_ws;
    u64*   best    = (u64*)ws;                            ws += (size_t)ROWS * 8;
    float* CBws    = (float*)ws;                          ws += (size_t)Nn * COLS * 4;
    float* cbn     = (float*)ws;                          ws += (size_t)Nn * 4;
    float* cbn_f   = (float*)ws;                          ws += (size_t)Nn * 4;
    float* xx      = (float*)ws;                          ws += (size_t)ROWS * 4;
    u32*   cbn_max = (u32*)ws;

    // bf16 copies live in d_out (128 MiB), only overwritten by k_epilogue at
    // the very end: Xh = 32 MiB at offset 0, CBf = 2 MiB at offset 64 MiB.
    short* Xh  = (short*)d_out;
    short* CBf = (short*)((char*)d_out + (64u << 20));

    float* Eout = (float*)d_out;
    float* Sout = Eout + (size_t)ROWS * COLS;

    k_prep<<<ROWS / 4, 256, 0, stream>>>(x, Xh, xx, best, cbn_max);
    k_codebook<<<Nn, 256, 0, stream>>>(fc, Wi, Wo, CBws, CBf, cbn, cbn_f, cbn_max);
    k_screen_fused<<<(ROWS / 128) * 2, 256, 0, stream>>>(Xh, CBf, x, CBws, cbn, cbn_f, xx, best, cbn_max);
    k_epilogue<<<ROWS / 4, 256, 0, stream>>>(x, CBws, best, Eout, Sout);
}

// Round 15
// 337.054 us; speedup vs baseline: 1.7292x; 1.7292x over previous
//
#include <hip/hip_runtime.h>
#include <hip/hip_bf16.h>
#include <stdint.h>

// Problem dims (fixed by reference)
#define Bq    8192
#define Hh    8
#define Dd    16
#define Kk    16
#define Nn    4096
#define DFf   16
#define ROWS  (Bq*Hh)          // 65536
#define COLS  (Dd*Kk)          // 256
#define EPSF  1e-6f

typedef unsigned long long u64;
typedef unsigned int u32;
typedef __attribute__((ext_vector_type(8)))  short bf16x8;
typedef __attribute__((ext_vector_type(16))) float f32x16;

// async global->LDS, 16B per lane; LDS dest = wave-uniform base + lane*16
#define GLOAD_LDS(g, l) __builtin_amdgcn_global_load_lds( \
    (const __attribute__((address_space(1))) u32*)(g), \
    (__attribute__((address_space(3))) u32*)(l), 16, 0, 0)

// ---------- helpers ----------
__device__ __forceinline__ float dot4(float4 a, float4 b) {
    return fmaf(a.x, b.x, fmaf(a.y, b.y, fmaf(a.z, b.z, a.w * b.w)));
}
__device__ __forceinline__ float wave_sum(float v) {
    #pragma unroll
    for (int m = 32; m > 0; m >>= 1) v += __shfl_xor(v, m, 64);
    return v;
}
__device__ __forceinline__ u32 f32_sortable(float f) {
    u32 u = __float_as_uint(f);
    return (u & 0x80000000u) ? ~u : (u | 0x80000000u);
}
// pack 2 floats -> 2 bf16 (RNE); low 16 bits = a
__device__ __forceinline__ u32 pk2(float a, float b) {
    union { __hip_bfloat162 h; u32 u; } v;
    v.h = __float22bfloat162_rn(make_float2(a, b));
    return v.u;
}
// exact fp32 rerank, R2's accepted expression tree (sequential fmaf over 64 float4s)
__device__ __forceinline__ void exact_rerank(const float* __restrict__ X,
                                             const float* __restrict__ CB,
                                             const float* __restrict__ xx,
                                             const float* __restrict__ cbn,
                                             int row, int col,
                                             u64* __restrict__ best) {
    const float4* xp = (const float4*)(X + (size_t)row * COLS);
    const float4* cp = (const float4*)(CB + (size_t)col * COLS);
    float d = 0.f;
    #pragma unroll 8
    for (int q = 0; q < 64; ++q) {
        float4 a = xp[q], b = cp[q];
        d = fmaf(a.x, b.x, d); d = fmaf(a.y, b.y, d);
        d = fmaf(a.z, b.z, d); d = fmaf(a.w, b.w, d);
    }
    float d2e = fmaf(-2.f, d, xx[row]) + cbn[col];
    u64 pk = ((u64)f32_sortable(d2e) << 32) | (u32)col;
    atomicMin(&best[row], pk);
}

// ---------- kernel 0: xx[r], X->bf16 (row-major), init best/cbn_max ----------
__global__ __launch_bounds__(256) void k_prep(const float* __restrict__ X,
                                              short* __restrict__ Xh,
                                              float* __restrict__ xx,
                                              u64* __restrict__ best,
                                              u32* __restrict__ cbn_max) {
    int r    = blockIdx.x * 4 + (threadIdx.x >> 6);
    int lane = threadIdx.x & 63;
    float4 v = *reinterpret_cast<const float4*>(X + (size_t)r * COLS + lane * 4);
    uint2 p; p.x = pk2(v.x, v.y); p.y = pk2(v.z, v.w);
    *reinterpret_cast<uint2*>(Xh + (size_t)r * COLS + lane * 4) = p;
    float s = wave_sum(v.x*v.x + v.y*v.y + v.z*v.z + v.w*v.w);
    if (lane == 0) { xx[r] = s; best[r] = ~0ull; }
    if (blockIdx.x == 0 && threadIdx.x == 0) *cbn_max = 0u;
}

// ---------- kernel 1: codebook fp32 + 32x32-FRAGMENT bf16 + cbn (+acc-order copy) ----------
// CBf layout (R10/R13, HW-verified): per 32-code tile (16 KB), frag f = kstep
// (0..15) is 1 KB: lane l = h*32 + c holds code row (tile*32 + c),
// k = kstep*16 + h*8 .. +8.  cbn_f = cbn permuted into acc order:
// cbn_f[tile*32 + h*16 + r] = cbn[tile*32 + crow(r,h)], crow = (r&3)+8*(r>>2)+4h.
__global__ __launch_bounds__(256) void k_codebook(const float* __restrict__ fc,
                                                  const float* __restrict__ Wi,
                                                  const float* __restrict__ Wo,
                                                  float* __restrict__ CB,
                                                  short* __restrict__ CBf,
                                                  float* __restrict__ cbn,
                                                  float* __restrict__ cbn_f,
                                                  u32* __restrict__ cbn_max) {
    int n = blockIdx.x, tid = threadIdx.x;
    int o = tid >> 4, k = tid & 15;
    __shared__ float fcs[256], wis[256], wos[256], hs[256], sq[256];
    __shared__ short cvs_sh[256];
    fcs[tid] = fc[(size_t)n * 256 + tid];
    wis[tid] = Wi[tid];
    wos[tid] = Wo[tid];
    __syncthreads();
    float hp = 0.f;
    #pragma unroll
    for (int i = 0; i < 16; ++i) hp = fmaf(wis[o*16 + i], fcs[i*16 + k], hp);
    hs[tid] = hp;
    __syncthreads();
    float h0 = hs[o * 16];
    float x3 = h0 * h0 * h0;
    float inner = 0.7978845608028654f * fmaf(0.044715f, x3, h0);
    float g = 0.5f * h0 * (1.f + tanhf(inner));
    float hg = hp * g;
    __syncthreads();
    hs[tid] = hg;
    __syncthreads();
    float cv = 0.f;
    #pragma unroll
    for (int i = 0; i < 16; ++i) cv = fmaf(wos[o*16 + i], hs[i*16 + k], cv);
    CB[(size_t)n * 256 + tid] = cv;
    { union { __hip_bfloat16 h; short s; } c; c.h = __float2bfloat16(cv);
      cvs_sh[tid] = c.s; }
    sq[tid] = cv * cv;
    __syncthreads();
    #pragma unroll
    for (int st = 128; st > 0; st >>= 1) {
        if (tid < st) sq[tid] += sq[tid + st];
        __syncthreads();
    }
    if (tid == 0) {
        cbn[n] = sq[0];
        atomicMax(cbn_max, __float_as_uint(sq[0]));
        int tile = n >> 5, c = n & 31;
        int h = (c >> 2) & 1, r = (c & 3) | ((c >> 3) << 2);
        cbn_f[tile * 32 + h * 16 + r] = sq[0];
    }
    // swizzled write: 32 chunks of 8 bf16 -> 32x32-fragment slots
    if (tid < 32) {
        int kc = tid;                      // 8-short chunk, k = kc*8
        int tile = n >> 5, c = n & 31;
        int kstep = kc >> 1, h = kc & 1;
        size_t off = (size_t)tile * 8192 + kstep * 512 + h * 256 + c * 8;
        *reinterpret_cast<uint4*>(CBf + off) =
            *reinterpret_cast<const uint4*>(&cvs_sh[kc * 8]);
    }
}

// ---------- kernel 2: swapped-operand 32x32 screen (R13) + 6-slot reg candidates ----------
// 512 blocks x 256 threads (4 waves x 32 x-rows), R13's HW-verified structure:
// lane owns one x-row; mfma(code_frag, x_frag); triple-buffer vmcnt(8) + two
// raw barriers per tile. NEW: candidates kept in SIX (g, code) register slots
// with stale-eviction instead of 8 LDS slots + inline-rerank overflow.
//   insert: find max-g slot (5 cmps); if its g > thr_now (stale: rmin only
//   decreases, so provably outside the FINAL window) replace it; else (7
//   simultaneously-fresh candidates, ~never) inline exact rerank.
// This removes R13's hidden stall: ~85%/step chance some lane did a ~1-2k cyc
// divergent inline rerank inside the barrier-coupled loop (prefix-min events
// H_128 + late delta-window hits vs only 8 slots). Post-loop: rerank only
// slots with g <= rmin_final + dlt (~1.5/lane, was ~9 -> 4x less gather).
// Safety: g(c*) <= rmin_final + dlt <= thr at all times -> argmin and all
// exact ties never evicted; exact fp32 rerank (R2 tree) + atomicMin merges.
__global__ __launch_bounds__(256, 2) void k_screen_fused(
        const short* __restrict__ Xh,
        const short* __restrict__ CBf,
        const float* __restrict__ X,
        const float* __restrict__ CB,
        const float* __restrict__ cbn,
        const float* __restrict__ cbn_f,
        const float* __restrict__ xx,
        u64* __restrict__ best,
        const u32* __restrict__ cbn_max) {
    __shared__ __align__(16) short Bs[3][8192];   // 3 x 16 KB code tiles
    __shared__ float cbn_fs[Nn];                  // 16 KB, acc-order

    const int tid  = threadIdx.x;
    const int lane = tid & 63;
    const int w    = tid >> 6;           // wave 0..3
    const int cl   = lane & 31;          // this lane's x-row (D col)
    const int kh   = lane >> 5;          // k-half / code-half
    const int bmBase = blockIdx.x * 128; // 32 x-rows per wave
    const int myrow  = bmBase + w * 32 + cl;

#define STAGE(t_, buf) do { \
        int _t = (t_); \
        _Pragma("unroll") \
        for (int _i = 0; _i < 4; ++_i) { \
            int _f = _i * 4 + w; \
            const short* _g = CBf + (size_t)_t * 8192 + _f * 512 + lane * 8; \
            GLOAD_LDS(_g, &Bs[(buf)][_f * 512]); \
        } \
    } while (0)

    // cbn_f -> LDS (acc-order, all 4096 codes)
    #pragma unroll
    for (int j = 0; j < 4; ++j)
        *reinterpret_cast<float4*>(&cbn_fs[tid * 16 + j * 4]) =
            *reinterpret_cast<const float4*>(&cbn_f[tid * 16 + j * 4]);

    // X fragments (B-operand): af[kstep], lane holds x-row myrow,
    // k = kstep*16 + kh*8 .. +8
    bf16x8 af[16];
    {
        const short* ap = Xh + ((size_t)myrow << 8) + kh * 8;
        #pragma unroll
        for (int ks = 0; ks < 16; ++ks)
            af[ks] = *reinterpret_cast<const bf16x8*>(ap + ks * 16);
    }

    // lane-local threshold slack (exact per-row)
    float dlt, rmin = 1e30f;
    {
        float xr = xx[myrow];
        dlt = fmaf(0.003f, sqrtf(xr * __uint_as_float(*cbn_max)), 0.01f);
    }

    __syncthreads();            // cbn_fs visible; vmcnt drained to 0 (prologue)

    STAGE(0, 0); STAGE(1, 1); STAGE(2, 2);   // 12 issues/thread outstanding

    // 6 candidate slots (registers, static indexing): g=1e30 means empty
    float g0 = 1e30f, g1 = 1e30f, g2 = 1e30f, g3 = 1e30f, g4 = 1e30f, g5 = 1e30f;
    u32   s0 = 0,     s1 = 0,     s2 = 0,     s3 = 0,     s4 = 0,     s5 = 0;

    int p = 0;

    for (int t = 0; t < 128; ++t) {
        asm volatile("s_waitcnt vmcnt(8)" ::: "memory");
        __builtin_amdgcn_sched_barrier(0);
        __builtin_amdgcn_s_barrier();               // (A) buf[p] ready
        __builtin_amdgcn_sched_barrier(0);

        f32x16 acc;
        #pragma unroll
        for (int r = 0; r < 16; ++r) acc[r] = 0.f;

        const short* Bt = &Bs[p][0];
        #pragma unroll
        for (int ks = 0; ks < 16; ++ks) {
            bf16x8 cf = *reinterpret_cast<const bf16x8*>(&Bt[ks * 512 + lane * 8]);
            acc = __builtin_amdgcn_mfma_f32_32x32x16_bf16(cf, af[ks], acc, 0, 0, 0);
        }

        // epilogue: g[r] = -2*dot + cbn; codes crow(r,kh) of tile t, row = cl
        float cbnv[16];
        #pragma unroll
        for (int q = 0; q < 4; ++q)
            *reinterpret_cast<float4*>(&cbnv[q * 4]) =
                *reinterpret_cast<const float4*>(&cbn_fs[t * 32 + kh * 16 + q * 4]);
        float gv[16], m = 1e30f;
        #pragma unroll
        for (int r = 0; r < 16; ++r) {
            gv[r] = fmaf(-2.f, acc[r], cbnv[r]);
            m = fminf(m, gv[r]);
        }
        m = fminf(m, __shfl_xor(m, 32, 64));        // other code-half, same row
        rmin = fminf(rmin, m);                      // running min incl. this tile
        float thr = rmin + dlt;
        #pragma unroll
        for (int r = 0; r < 16; ++r) {
            if (gv[r] <= thr) {
                u32 code = (u32)(t * 32 + (r & 3) + 8 * (r >> 2) + 4 * kh);
                // find max-g slot (stale candidates have large g)
                float mg = g0; int mi = 0;
                if (g1 > mg) { mg = g1; mi = 1; }
                if (g2 > mg) { mg = g2; mi = 2; }
                if (g3 > mg) { mg = g3; mi = 3; }
                if (g4 > mg) { mg = g4; mi = 4; }
                if (g5 > mg) { mg = g5; mi = 5; }
                if (mg > thr) {         // stale (or empty): provably outside final window
                    if      (mi == 0) { g0 = gv[r]; s0 = code; }
                    else if (mi == 1) { g1 = gv[r]; s1 = code; }
                    else if (mi == 2) { g2 = gv[r]; s2 = code; }
                    else if (mi == 3) { g3 = gv[r]; s3 = code; }
                    else if (mi == 4) { g4 = gv[r]; s4 = code; }
                    else              { g5 = gv[r]; s5 = code; }
                } else {                // 7 fresh candidates at once: ~never
                    exact_rerank(X, CB, xx, cbn, myrow, (int)code, best);
                }
            }
        }

        __builtin_amdgcn_sched_barrier(0);
        __builtin_amdgcn_s_barrier();               // (B) buf[p] free
        __builtin_amdgcn_sched_barrier(0);
        STAGE((t + 3) & 127, p);    // wrap keeps vmcnt count uniform
        p = (p == 2) ? 0 : p + 1;
    }

    // post-loop: exact fp32 rerank of slots still within the FINAL window
    float thrF = rmin + dlt;
    if (g0 <= thrF) exact_rerank(X, CB, xx, cbn, myrow, (int)s0, best);
    if (g1 <= thrF) exact_rerank(X, CB, xx, cbn, myrow, (int)s1, best);
    if (g2 <= thrF) exact_rerank(X, CB, xx, cbn, myrow, (int)s2, best);
    if (g3 <= thrF) exact_rerank(X, CB, xx, cbn, myrow, (int)s3, best);
    if (g4 <= thrF) exact_rerank(X, CB, xx, cbn, myrow, (int)s4, best);
    if (g5 <= thrF) exact_rerank(X, CB, xx, cbn, myrow, (int)s5, best);
#undef STAGE
}

// ---------- kernel 3: gather e, Householder STE ----------
__global__ __launch_bounds__(256) void k_epilogue(const float* __restrict__ X,
                                                  const float* __restrict__ CB,
                                                  const u64* __restrict__ best,
                                                  float* __restrict__ Eout,
                                                  float* __restrict__ Sout) {
    int r    = blockIdx.x * 4 + (threadIdx.x >> 6);
    int lane = threadIdx.x & 63;
    int idx  = (int)(best[r] & 0xffffffffull);

    float4 xv = *reinterpret_cast<const float4*>(X  + (size_t)r   * COLS + lane * 4);
    float4 ev = *reinterpret_cast<const float4*>(CB + (size_t)idx * COLS + lane * 4);

    float xn2 = wave_sum(dot4(xv, xv));
    float en2 = wave_sum(dot4(ev, ev));
    float xn = sqrtf(xn2), en = sqrtf(en2);
    float invx = 1.f / fmaxf(xn, EPSF);
    float inve = 1.f / fmaxf(en, EPSF);

    float4 xd, ed, sd0;
    xd.x = xv.x*invx; xd.y = xv.y*invx; xd.z = xv.z*invx; xd.w = xv.w*invx;
    ed.x = ev.x*inve; ed.y = ev.y*inve; ed.z = ev.z*inve; ed.w = ev.w*inve;
    sd0.x = xd.x+ed.x; sd0.y = xd.y+ed.y; sd0.z = xd.z+ed.z; sd0.w = xd.w+ed.w;

    float sdn2 = wave_sum(dot4(sd0, sd0));
    float p1   = wave_sum(dot4(sd0, xv));
    float p2   = wave_sum(dot4(xd,  xv));
    float invs = 1.f / fmaxf(sqrtf(sdn2), EPSF);

    float csd = -2.f * invs * invs * p1;
    float ced =  2.f * p2;
    float4 rr;
    rr.x = fmaf(csd, sd0.x, fmaf(ced, ed.x, xv.x));
    rr.y = fmaf(csd, sd0.y, fmaf(ced, ed.y, xv.y));
    rr.z = fmaf(csd, sd0.z, fmaf(ced, ed.z, xv.z));
    rr.w = fmaf(csd, sd0.w, fmaf(ced, ed.w, xv.w));
    float sc = en * invx;
    float4 sv; sv.x = rr.x*sc; sv.y = rr.y*sc; sv.z = rr.z*sc; sv.w = rr.w*sc;

    *reinterpret_cast<float4*>(Eout + (size_t)r * COLS + lane * 4) = ev;
    *reinterpret_cast<float4*>(Sout + (size_t)r * COLS + lane * 4) = sv;
}

// ---------- launcher ----------
extern "C" void kernel_launch(void* const* d_in, const int* in_sizes, int n_in,
                              void* d_out, int out_size, void* d_ws, size_t ws_size,
                              hipStream_t stream) {
    const float* x  = (const float*)d_in[0];
    const float* fc = (const float*)d_in[1];
    const float* Wi = (const float*)d_in[2];
    const float* Wo = (const float*)d_in[3];

    // ws layout (~5 MB)
    char* ws = (char*)d_ws;
    u64*   best    = (u64*)ws;                            ws += (size_t)ROWS * 8;
    float* CBws    = (float*)ws;                          ws += (size_t)Nn * COLS * 4;
    float* cbn     = (float*)ws;                          ws += (size_t)Nn * 4;
    float* cbn_f   = (float*)ws;                          ws += (size_t)Nn * 4;
    float* xx      = (float*)ws;                          ws += (size_t)ROWS * 4;
    u32*   cbn_max = (u32*)ws;

    // bf16 copies live in d_out (128 MiB), only overwritten by k_epilogue at
    // the very end: Xh = 32 MiB at offset 0, CBf = 2 MiB at offset 64 MiB.
    short* Xh  = (short*)d_out;
    short* CBf = (short*)((char*)d_out + (64u << 20));

    float* Eout = (float*)d_out;
    float* Sout = Eout + (size_t)ROWS * COLS;

    k_prep<<<ROWS / 4, 256, 0, stream>>>(x, Xh, xx, best, cbn_max);
    k_codebook<<<Nn, 256, 0, stream>>>(fc, Wi, Wo, CBws, CBf, cbn, cbn_f, cbn_max);
    k_screen_fused<<<ROWS / 128, 256, 0, stream>>>(Xh, CBf, x, CBws, cbn, cbn_f, xx, best, cbn_max);
    k_epilogue<<<ROWS / 4, 256, 0, stream>>>(x, CBws, best, Eout, Sout);
}

// Round 16
// 324.361 us; speedup vs baseline: 1.7969x; 1.0391x over previous
//
#include <hip/hip_runtime.h>
#include <hip/hip_bf16.h>
#include <stdint.h>

// Problem dims (fixed by reference)
#define Bq    8192
#define Hh    8
#define Dd    16
#define Kk    16
#define Nn    4096
#define DFf   16
#define ROWS  (Bq*Hh)          // 65536
#define COLS  (Dd*Kk)          // 256
#define EPSF  1e-6f

typedef unsigned long long u64;
typedef unsigned int u32;
typedef __attribute__((ext_vector_type(8)))  short bf16x8;
typedef __attribute__((ext_vector_type(16))) float f32x16;

// async global->LDS, 16B per lane; LDS dest = wave-uniform base + lane*16
#define GLOAD_LDS(g, l) __builtin_amdgcn_global_load_lds( \
    (const __attribute__((address_space(1))) u32*)(g), \
    (__attribute__((address_space(3))) u32*)(l), 16, 0, 0)

// ---------- helpers ----------
__device__ __forceinline__ float dot4(float4 a, float4 b) {
    return fmaf(a.x, b.x, fmaf(a.y, b.y, fmaf(a.z, b.z, a.w * b.w)));
}
__device__ __forceinline__ float wave_sum(float v) {
    #pragma unroll
    for (int m = 32; m > 0; m >>= 1) v += __shfl_xor(v, m, 64);
    return v;
}
__device__ __forceinline__ u32 f32_sortable(float f) {
    u32 u = __float_as_uint(f);
    return (u & 0x80000000u) ? ~u : (u | 0x80000000u);
}
// pack 2 floats -> 2 bf16 (RNE); low 16 bits = a
__device__ __forceinline__ u32 pk2(float a, float b) {
    union { __hip_bfloat162 h; u32 u; } v;
    v.h = __float22bfloat162_rn(make_float2(a, b));
    return v.u;
}
// exact fp32 rerank, R2's accepted expression tree (sequential fmaf over 64 float4s)
__device__ __forceinline__ void exact_rerank(const float* __restrict__ X,
                                             const float* __restrict__ CB,
                                             const float* __restrict__ xx,
                                             const float* __restrict__ cbn,
                                             int row, int col,
                                             u64* __restrict__ best) {
    const float4* xp = (const float4*)(X + (size_t)row * COLS);
    const float4* cp = (const float4*)(CB + (size_t)col * COLS);
    float d = 0.f;
    #pragma unroll 8
    for (int q = 0; q < 64; ++q) {
        float4 a = xp[q], b = cp[q];
        d = fmaf(a.x, b.x, d); d = fmaf(a.y, b.y, d);
        d = fmaf(a.z, b.z, d); d = fmaf(a.w, b.w, d);
    }
    float d2e = fmaf(-2.f, d, xx[row]) + cbn[col];
    u64 pk = ((u64)f32_sortable(d2e) << 32) | (u32)col;
    atomicMin(&best[row], pk);
}

// ---------- kernel 0: xx[r], X->bf16 (row-major), init best/cbn_max ----------
__global__ __launch_bounds__(256) void k_prep(const float* __restrict__ X,
                                              short* __restrict__ Xh,
                                              float* __restrict__ xx,
                                              u64* __restrict__ best,
                                              u32* __restrict__ cbn_max) {
    int r    = blockIdx.x * 4 + (threadIdx.x >> 6);
    int lane = threadIdx.x & 63;
    float4 v = *reinterpret_cast<const float4*>(X + (size_t)r * COLS + lane * 4);
    uint2 p; p.x = pk2(v.x, v.y); p.y = pk2(v.z, v.w);
    *reinterpret_cast<uint2*>(Xh + (size_t)r * COLS + lane * 4) = p;
    float s = wave_sum(v.x*v.x + v.y*v.y + v.z*v.z + v.w*v.w);
    if (lane == 0) { xx[r] = s; best[r] = ~0ull; }
    if (blockIdx.x == 0 && threadIdx.x == 0) *cbn_max = 0u;
}

// ---------- kernel 1: codebook fp32 + 32x32-FRAGMENT bf16 + cbn (+acc-order copy) ----------
// CBf layout (R10/R13, HW-verified): per 32-code tile (16 KB), frag f = kstep
// (0..15) is 1 KB: lane l = h*32 + c holds code row (tile*32 + c),
// k = kstep*16 + h*8 .. +8.  cbn_f = cbn permuted into acc order:
// cbn_f[tile*32 + h*16 + r] = cbn[tile*32 + crow(r,h)], crow = (r&3)+8*(r>>2)+4h.
__global__ __launch_bounds__(256) void k_codebook(const float* __restrict__ fc,
                                                  const float* __restrict__ Wi,
                                                  const float* __restrict__ Wo,
                                                  float* __restrict__ CB,
                                                  short* __restrict__ CBf,
                                                  float* __restrict__ cbn,
                                                  float* __restrict__ cbn_f,
                                                  u32* __restrict__ cbn_max) {
    int n = blockIdx.x, tid = threadIdx.x;
    int o = tid >> 4, k = tid & 15;
    __shared__ float fcs[256], wis[256], wos[256], hs[256], sq[256];
    __shared__ short cvs_sh[256];
    fcs[tid] = fc[(size_t)n * 256 + tid];
    wis[tid] = Wi[tid];
    wos[tid] = Wo[tid];
    __syncthreads();
    float hp = 0.f;
    #pragma unroll
    for (int i = 0; i < 16; ++i) hp = fmaf(wis[o*16 + i], fcs[i*16 + k], hp);
    hs[tid] = hp;
    __syncthreads();
    float h0 = hs[o * 16];
    float x3 = h0 * h0 * h0;
    float inner = 0.7978845608028654f * fmaf(0.044715f, x3, h0);
    float g = 0.5f * h0 * (1.f + tanhf(inner));
    float hg = hp * g;
    __syncthreads();
    hs[tid] = hg;
    __syncthreads();
    float cv = 0.f;
    #pragma unroll
    for (int i = 0; i < 16; ++i) cv = fmaf(wos[o*16 + i], hs[i*16 + k], cv);
    CB[(size_t)n * 256 + tid] = cv;
    { union { __hip_bfloat16 h; short s; } c; c.h = __float2bfloat16(cv);
      cvs_sh[tid] = c.s; }
    sq[tid] = cv * cv;
    __syncthreads();
    #pragma unroll
    for (int st = 128; st > 0; st >>= 1) {
        if (tid < st) sq[tid] += sq[tid + st];
        __syncthreads();
    }
    if (tid == 0) {
        cbn[n] = sq[0];
        atomicMax(cbn_max, __float_as_uint(sq[0]));
        int tile = n >> 5, c = n & 31;
        int h = (c >> 2) & 1, r = (c & 3) | ((c >> 3) << 2);
        cbn_f[tile * 32 + h * 16 + r] = sq[0];
    }
    // swizzled write: 32 chunks of 8 bf16 -> 32x32-fragment slots
    if (tid < 32) {
        int kc = tid;                      // 8-short chunk, k = kc*8
        int tile = n >> 5, c = n & 31;
        int kstep = kc >> 1, h = kc & 1;
        size_t off = (size_t)tile * 8192 + kstep * 512 + h * 256 + c * 8;
        *reinterpret_cast<uint4*>(CBf + off) =
            *reinterpret_cast<const uint4*>(&cvs_sh[kc * 8]);
    }
}

// ---------- kernel 2: swapped-operand 32x32 screen, 2 TILES PER BARRIER PAIR ----------
// 512 blocks x 256 threads (4 waves x 32 x-rows), R15's HW-verified per-wave
// structure (lane owns one x-row; mfma(code_frag, x_frag); register-only
// epilogue + 1 shfl/tile; 6-slot stale-eviction candidates). NEW vs R15:
// each step stages + computes a PAIR of 16 KB tiles through a DOUBLE 32 KB
// buffer -> 64 steps instead of 128: per-tile barrier/vmcnt/lockstep overhead
// halves, and the two tiles give TWO independent 16-deep MFMA acc chains
// (2x ILP where 2 waves/SIMD can't hide MFMA latency alone).
//   prologue: STAGE2(P0,buf0), STAGE2(P1,buf1)   (16 issues/thread)
//   step s:   s_waitcnt vmcnt(8)  -> pair s landed (pair s+1 in flight)
//             s_barrier A; 32 ds_read_b128 + 32 MFMA (chains aA,aB) +
//             2 epilogues; s_barrier B; STAGE2(pair (s+2)&63, buf s&1)
// Slack per stage = one full step (~2500 cyc) >> L2 latency; count uniform.
// Candidate safety unchanged: rmin only decreases; argmin + exact ties never
// evicted; exact fp32 rerank (R2 tree) + packed atomicMin merges.
__global__ __launch_bounds__(256, 2) void k_screen_fused(
        const short* __restrict__ Xh,
        const short* __restrict__ CBf,
        const float* __restrict__ X,
        const float* __restrict__ CB,
        const float* __restrict__ cbn,
        const float* __restrict__ cbn_f,
        const float* __restrict__ xx,
        u64* __restrict__ best,
        const u32* __restrict__ cbn_max) {
    __shared__ __align__(16) short Bs[2][16384];  // 2 x 32 KB tile pairs
    __shared__ float cbn_fs[Nn];                  // 16 KB, acc-order

    const int tid  = threadIdx.x;
    const int lane = tid & 63;
    const int w    = tid >> 6;           // wave 0..3
    const int cl   = lane & 31;          // this lane's x-row (D col)
    const int kh   = lane >> 5;          // k-half / code-half
    const int bmBase = blockIdx.x * 128; // 32 x-rows per wave
    const int myrow  = bmBase + w * 32 + cl;

// stage tile PAIR P (tiles 2P, 2P+1) into Bs[buf]: 8 gloads/thread
#define STAGE2(P_, buf) do { \
        int _P = (P_); \
        _Pragma("unroll") \
        for (int _i = 0; _i < 8; ++_i) { \
            int _half = _i >> 2; \
            int _f = (_i & 3) * 4 + w; \
            const short* _g = CBf + (size_t)(_P * 2 + _half) * 8192 \
                            + _f * 512 + lane * 8; \
            GLOAD_LDS(_g, &Bs[(buf)][_half * 8192 + _f * 512]); \
        } \
    } while (0)

    // cbn_f -> LDS (acc-order, all 4096 codes)
    #pragma unroll
    for (int j = 0; j < 4; ++j)
        *reinterpret_cast<float4*>(&cbn_fs[tid * 16 + j * 4]) =
            *reinterpret_cast<const float4*>(&cbn_f[tid * 16 + j * 4]);

    // X fragments (B-operand): af[kstep], lane holds x-row myrow,
    // k = kstep*16 + kh*8 .. +8
    bf16x8 af[16];
    {
        const short* ap = Xh + ((size_t)myrow << 8) + kh * 8;
        #pragma unroll
        for (int ks = 0; ks < 16; ++ks)
            af[ks] = *reinterpret_cast<const bf16x8*>(ap + ks * 16);
    }

    // lane-local threshold slack (exact per-row)
    float dlt, rmin = 1e30f;
    {
        float xr = xx[myrow];
        dlt = fmaf(0.003f, sqrtf(xr * __uint_as_float(*cbn_max)), 0.01f);
    }

    __syncthreads();            // cbn_fs visible; vmcnt drained to 0 (prologue)

    STAGE2(0, 0); STAGE2(1, 1);   // 16 issues/thread outstanding

    // 6 candidate slots (registers, static indexing): g=1e30 means empty
    float g0 = 1e30f, g1 = 1e30f, g2 = 1e30f, g3 = 1e30f, g4 = 1e30f, g5 = 1e30f;
    u32   s0 = 0,     s1 = 0,     s2 = 0,     s3 = 0,     s4 = 0,     s5 = 0;

// per-tile epilogue + candidate insert (register-only, 1 shfl)
#define EPI(accv, tile_) do { \
        int _t = (tile_); \
        float cbnv[16]; \
        _Pragma("unroll") \
        for (int _q = 0; _q < 4; ++_q) \
            *reinterpret_cast<float4*>(&cbnv[_q * 4]) = \
                *reinterpret_cast<const float4*>(&cbn_fs[_t * 32 + kh * 16 + _q * 4]); \
        float gv[16], _m = 1e30f; \
        _Pragma("unroll") \
        for (int _r = 0; _r < 16; ++_r) { \
            gv[_r] = fmaf(-2.f, (accv)[_r], cbnv[_r]); \
            _m = fminf(_m, gv[_r]); \
        } \
        _m = fminf(_m, __shfl_xor(_m, 32, 64)); \
        rmin = fminf(rmin, _m); \
        float _thr = rmin + dlt; \
        _Pragma("unroll") \
        for (int _r = 0; _r < 16; ++_r) { \
            if (gv[_r] <= _thr) { \
                u32 _code = (u32)(_t * 32 + (_r & 3) + 8 * (_r >> 2) + 4 * kh); \
                float _mg = g0; int _mi = 0; \
                if (g1 > _mg) { _mg = g1; _mi = 1; } \
                if (g2 > _mg) { _mg = g2; _mi = 2; } \
                if (g3 > _mg) { _mg = g3; _mi = 3; } \
                if (g4 > _mg) { _mg = g4; _mi = 4; } \
                if (g5 > _mg) { _mg = g5; _mi = 5; } \
                if (_mg > _thr) { \
                    if      (_mi == 0) { g0 = gv[_r]; s0 = _code; } \
                    else if (_mi == 1) { g1 = gv[_r]; s1 = _code; } \
                    else if (_mi == 2) { g2 = gv[_r]; s2 = _code; } \
                    else if (_mi == 3) { g3 = gv[_r]; s3 = _code; } \
                    else if (_mi == 4) { g4 = gv[_r]; s4 = _code; } \
                    else               { g5 = gv[_r]; s5 = _code; } \
                } else { \
                    exact_rerank(X, CB, xx, cbn, myrow, (int)_code, best); \
                } \
            } \
        } \
    } while (0)

    for (int s = 0; s < 64; ++s) {          // 64 steps x 2 tiles
        asm volatile("s_waitcnt vmcnt(8)" ::: "memory");
        __builtin_amdgcn_sched_barrier(0);
        __builtin_amdgcn_s_barrier();               // (A) buf[s&1] ready
        __builtin_amdgcn_sched_barrier(0);

        f32x16 aA, aB;
        #pragma unroll
        for (int r = 0; r < 16; ++r) { aA[r] = 0.f; aB[r] = 0.f; }

        const short* Bt = &Bs[s & 1][0];
        #pragma unroll
        for (int ks = 0; ks < 16; ++ks) {           // two independent chains
            bf16x8 cfA = *reinterpret_cast<const bf16x8*>(&Bt[ks * 512 + lane * 8]);
            bf16x8 cfB = *reinterpret_cast<const bf16x8*>(&Bt[8192 + ks * 512 + lane * 8]);
            aA = __builtin_amdgcn_mfma_f32_32x32x16_bf16(cfA, af[ks], aA, 0, 0, 0);
            aB = __builtin_amdgcn_mfma_f32_32x32x16_bf16(cfB, af[ks], aB, 0, 0, 0);
        }

        EPI(aA, s * 2);
        EPI(aB, s * 2 + 1);

        __builtin_amdgcn_sched_barrier(0);
        __builtin_amdgcn_s_barrier();               // (B) buf[s&1] free
        __builtin_amdgcn_sched_barrier(0);
        STAGE2((s + 2) & 63, s & 1);    // wrap keeps vmcnt count uniform
    }

    // post-loop: exact fp32 rerank of slots still within the FINAL window
    float thrF = rmin + dlt;
    if (g0 <= thrF) exact_rerank(X, CB, xx, cbn, myrow, (int)s0, best);
    if (g1 <= thrF) exact_rerank(X, CB, xx, cbn, myrow, (int)s1, best);
    if (g2 <= thrF) exact_rerank(X, CB, xx, cbn, myrow, (int)s2, best);
    if (g3 <= thrF) exact_rerank(X, CB, xx, cbn, myrow, (int)s3, best);
    if (g4 <= thrF) exact_rerank(X, CB, xx, cbn, myrow, (int)s4, best);
    if (g5 <= thrF) exact_rerank(X, CB, xx, cbn, myrow, (int)s5, best);
#undef EPI
#undef STAGE2
}

// ---------- kernel 3: gather e, Householder STE ----------
__global__ __launch_bounds__(256) void k_epilogue(const float* __restrict__ X,
                                                  const float* __restrict__ CB,
                                                  const u64* __restrict__ best,
                                                  float* __restrict__ Eout,
                                                  float* __restrict__ Sout) {
    int r    = blockIdx.x * 4 + (threadIdx.x >> 6);
    int lane = threadIdx.x & 63;
    int idx  = (int)(best[r] & 0xffffffffull);

    float4 xv = *reinterpret_cast<const float4*>(X  + (size_t)r   * COLS + lane * 4);
    float4 ev = *reinterpret_cast<const float4*>(CB + (size_t)idx * COLS + lane * 4);

    float xn2 = wave_sum(dot4(xv, xv));
    float en2 = wave_sum(dot4(ev, ev));
    float xn = sqrtf(xn2), en = sqrtf(en2);
    float invx = 1.f / fmaxf(xn, EPSF);
    float inve = 1.f / fmaxf(en, EPSF);

    float4 xd, ed, sd0;
    xd.x = xv.x*invx; xd.y = xv.y*invx; xd.z = xv.z*invx; xd.w = xv.w*invx;
    ed.x = ev.x*inve; ed.y = ev.y*inve; ed.z = ev.z*inve; ed.w = ev.w*inve;
    sd0.x = xd.x+ed.x; sd0.y = xd.y+ed.y; sd0.z = xd.z+ed.z; sd0.w = xd.w+ed.w;

    float sdn2 = wave_sum(dot4(sd0, sd0));
    float p1   = wave_sum(dot4(sd0, xv));
    float p2   = wave_sum(dot4(xd,  xv));
    float invs = 1.f / fmaxf(sqrtf(sdn2), EPSF);

    float csd = -2.f * invs * invs * p1;
    float ced =  2.f * p2;
    float4 rr;
    rr.x = fmaf(csd, sd0.x, fmaf(ced, ed.x, xv.x));
    rr.y = fmaf(csd, sd0.y, fmaf(ced, ed.y, xv.y));
    rr.z = fmaf(csd, sd0.z, fmaf(ced, ed.z, xv.z));
    rr.w = fmaf(csd, sd0.w, fmaf(ced, ed.w, xv.w));
    float sc = en * invx;
    float4 sv; sv.x = rr.x*sc; sv.y = rr.y*sc; sv.z = rr.z*sc; sv.w = rr.w*sc;

    *reinterpret_cast<float4*>(Eout + (size_t)r * COLS + lane * 4) = ev;
    *reinterpret_cast<float4*>(Sout + (size_t)r * COLS + lane * 4) = sv;
}

// ---------- launcher ----------
extern "C" void kernel_launch(void* const* d_in, const int* in_sizes, int n_in,
                              void* d_out, int out_size, void* d_ws, size_t ws_size,
                              hipStream_t stream) {
    const float* x  = (const float*)d_in[0];
    const float* fc = (const float*)d_in[1];
    const float* Wi = (const float*)d_in[2];
    const float* Wo = (const float*)d_in[3];

    // ws layout (~5 MB)
    char* ws = (char*)d_ws;
    u64*   best    = (u64*)ws;                            ws += (size_t)ROWS * 8;
    float* CBws    = (float*)ws;                          ws += (size_t)Nn * COLS * 4;
    float* cbn     = (float*)ws;                          ws += (size_t)Nn * 4;
    float* cbn_f   = (float*)ws;                          ws += (size_t)Nn * 4;
    float* xx      = (float*)ws;                          ws += (size_t)ROWS * 4;
    u32*   cbn_max = (u32*)ws;

    // bf16 copies live in d_out (128 MiB), only overwritten by k_epilogue at
    // the very end: Xh = 32 MiB at offset 0, CBf = 2 MiB at offset 64 MiB.
    short* Xh  = (short*)d_out;
    short* CBf = (short*)((char*)d_out + (64u << 20));

    float* Eout = (float*)d_out;
    float* Sout = Eout + (size_t)ROWS * COLS;

    k_prep<<<ROWS / 4, 256, 0, stream>>>(x, Xh, xx, best, cbn_max);
    k_codebook<<<Nn, 256, 0, stream>>>(fc, Wi, Wo, CBws, CBf, cbn, cbn_f, cbn_max);
    k_screen_fused<<<ROWS / 128, 256, 0, stream>>>(Xh, CBf, x, CBws, cbn, cbn_f, xx, best, cbn_max);
    k_epilogue<<<ROWS / 4, 256, 0, stream>>>(x, CBws, best, Eout, Sout);
}